// Round 1
// baseline (183.422 us; speedup 1.0000x reference)
//
#include <hip/hip_runtime.h>
#include <hip/hip_bf16.h>

typedef __bf16 bf16x8 __attribute__((ext_vector_type(8)));
typedef float  f32x4  __attribute__((ext_vector_type(4)));

#define Bsz 64
#define Tdim 2048
#define Edim 512
#define Ddim 1024
#define Udim 128

__device__ inline unsigned short f2bf(float f) {
    union { float f; unsigned int u; } x{f};
    unsigned int r = x.u + 0x7FFFu + ((x.u >> 16) & 1u);   // RNE
    return (unsigned short)(r >> 16);
}

// ---- K0a: Wk (U,E) fp32 -> bf16 into ws ----
__global__ __launch_bounds__(256) void k_cast_wk(const float* __restrict__ Wk,
                                                 unsigned short* __restrict__ out) {
    int i = (blockIdx.x * 256 + threadIdx.x) * 4;           // 64 blocks -> 65536 elems
    float4 v = *reinterpret_cast<const float4*>(Wk + i);
    ushort4 h = make_ushort4(f2bf(v.x), f2bf(v.y), f2bf(v.z), f2bf(v.w));
    *reinterpret_cast<ushort4*>(out + i) = h;
}

// ---- K0b: qb[b,u] = queries[b]·Wq[u] + b[u] + conv_b[u] ----
__global__ __launch_bounds__(256) void k_prep_qb(const float* __restrict__ q,
                                                 const float* __restrict__ Wq,
                                                 const float* __restrict__ bparam,
                                                 const float* __restrict__ convb,
                                                 float* __restrict__ qb) {
    int gw   = blockIdx.x * 4 + (threadIdx.x >> 6);         // 2048 blocks * 4 waves = 8192 = B*U
    int lane = threadIdx.x & 63;
    int b = gw >> 7, u = gw & 127;
    const float* qr = q  + (size_t)b * Ddim;
    const float* wr = Wq + (size_t)u * Ddim;
    float s = 0.f;
    #pragma unroll
    for (int i = 0; i < 4; ++i) {
        int base = lane * 16 + i * 4;
        float4 a = *reinterpret_cast<const float4*>(qr + base);
        float4 w = *reinterpret_cast<const float4*>(wr + base);
        s += a.x * w.x + a.y * w.y + a.z * w.z + a.w * w.w;
    }
    #pragma unroll
    for (int m = 32; m; m >>= 1) s += __shfl_xor(s, m);
    if (lane == 0) qb[gw] = s + bparam[u] + convb[u];
}

// ---- K1: fused score = v·tanh(enc@Wk^T + qb + conv(prev)) + v_b ----
// block: 256 thr (4 waves), tile 64 t x 128 u, K-chunks of 64 over E
__global__ __launch_bounds__(256) void k_score(const float* __restrict__ enc,
                                               const float* __restrict__ prev,
                                               const unsigned short* __restrict__ wkbf,
                                               const float* __restrict__ qb,
                                               const float* __restrict__ conv_w,
                                               const float* __restrict__ v_w,
                                               const float* __restrict__ v_b,
                                               float* __restrict__ score_out) {
    __shared__ alignas(16) unsigned short At[64 * 64];      // 8 KB, swizzled
    __shared__ alignas(16) unsigned short Bt[128 * 64];     // 16 KB, swizzled
    __shared__ float s_prev[66];
    __shared__ float s_qb[128];
    __shared__ float s_vw[128];
    __shared__ float s_cw[3][128];

    const int tid  = threadIdx.x;
    const int b    = blockIdx.y;
    const int t0   = blockIdx.x * 64;
    const int lane = tid & 63, wid = tid >> 6;

    if (tid < 128) {
        s_qb[tid]   = qb[b * 128 + tid];
        s_vw[tid]   = v_w[tid];
        s_cw[0][tid] = conv_w[tid * 3 + 0];
        s_cw[1][tid] = conv_w[tid * 3 + 1];
        s_cw[2][tid] = conv_w[tid * 3 + 2];
    }
    if (tid < 66) {
        int idx = t0 - 1 + tid;
        s_prev[tid] = (idx >= 0 && idx < Tdim) ? prev[b * Tdim + idx] : 0.f;
    }

    f32x4 acc[8];
    #pragma unroll
    for (int n = 0; n < 8; ++n) acc[n] = (f32x4){0.f, 0.f, 0.f, 0.f};

    const float* encb = enc + ((size_t)b * Tdim + t0) * Edim;

    for (int e0 = 0; e0 < Edim; e0 += 64) {
        // stage A: enc[t0..t0+63][e0..e0+63] -> bf16, XOR-swizzled rows of 128B
        #pragma unroll
        for (int i = 0; i < 4; ++i) {
            int lin = tid + i * 256;
            int r = lin >> 4, c4 = lin & 15;
            float4 v = *reinterpret_cast<const float4*>(encb + (size_t)r * Edim + e0 + c4 * 4);
            ushort4 h = make_ushort4(f2bf(v.x), f2bf(v.y), f2bf(v.z), f2bf(v.w));
            int off = (r * 128 + c4 * 8) ^ ((r & 7) << 4);
            *reinterpret_cast<ushort4*>(reinterpret_cast<char*>(At) + off) = h;
        }
        // stage B: Wk_bf16[0..127][e0..e0+63], same swizzle
        #pragma unroll
        for (int i = 0; i < 4; ++i) {
            int lin = tid + i * 256;
            int u = lin >> 3, c8 = lin & 7;
            uint4 w = *reinterpret_cast<const uint4*>(wkbf + (size_t)u * Edim + e0 + c8 * 8);
            int off = (u * 128 + c8 * 16) ^ ((u & 7) << 4);
            *reinterpret_cast<uint4*>(reinterpret_cast<char*>(Bt) + off) = w;
        }
        __syncthreads();
        #pragma unroll
        for (int kk = 0; kk < 2; ++kk) {
            int ar = wid * 16 + (lane & 15);
            int abyte = (ar * 128 + kk * 64 + (lane >> 4) * 16) ^ ((ar & 7) << 4);
            bf16x8 af = *reinterpret_cast<const bf16x8*>(reinterpret_cast<char*>(At) + abyte);
            #pragma unroll
            for (int n = 0; n < 8; ++n) {
                int br = n * 16 + (lane & 15);
                int bbyte = (br * 128 + kk * 64 + (lane >> 4) * 16) ^ ((br & 7) << 4);
                bf16x8 bv = *reinterpret_cast<const bf16x8*>(reinterpret_cast<char*>(Bt) + bbyte);
                acc[n] = __builtin_amdgcn_mfma_f32_16x16x32_bf16(af, bv, acc[n], 0, 0, 0);
            }
        }
        __syncthreads();
    }

    // epilogue: w = tanh(acc + qb + conv); score = sum_u v_w[u]*w
    float sc[4] = {0.f, 0.f, 0.f, 0.f};
    #pragma unroll
    for (int n = 0; n < 8; ++n) {
        int u = n * 16 + (lane & 15);
        float c0 = s_cw[0][u], c1 = s_cw[1][u], c2 = s_cw[2][u];
        float qbu = s_qb[u], vwu = s_vw[u];
        #pragma unroll
        for (int j = 0; j < 4; ++j) {
            int tl = wid * 16 + (lane >> 4) * 4 + j;
            float conv = s_prev[tl] * c0 + s_prev[tl + 1] * c1 + s_prev[tl + 2] * c2;
            sc[j] += vwu * tanhf(acc[n][j] + qbu + conv);
        }
    }
    #pragma unroll
    for (int j = 0; j < 4; ++j) {
        sc[j] += __shfl_xor(sc[j], 1);
        sc[j] += __shfl_xor(sc[j], 2);
        sc[j] += __shfl_xor(sc[j], 4);
        sc[j] += __shfl_xor(sc[j], 8);
    }
    if ((lane & 15) == 0) {
        float vb = v_b[0];
        int tl = wid * 16 + (lane >> 4) * 4;
        #pragma unroll
        for (int j = 0; j < 4; ++j)
            score_out[b * Tdim + t0 + tl + j] = sc[j] + vb;
    }
}

// ---- K2: masked softmax over T, in place on d_out's attn slot ----
__global__ __launch_bounds__(256) void k_softmax(float* __restrict__ attn,
                                                 const int* __restrict__ lengths) {
    int b = blockIdx.x, tid = threadIdx.x;
    int len = lengths[b];
    float* row = attn + (size_t)b * Tdim;
    float v[8];
    float m = -3.4e38f;
    #pragma unroll
    for (int i = 0; i < 8; ++i) {
        int t = tid + i * 256;
        v[i] = (t < len) ? row[t] : -3.4e38f;
        m = fmaxf(m, v[i]);
    }
    __shared__ float redm[4];
    #pragma unroll
    for (int s = 32; s; s >>= 1) m = fmaxf(m, __shfl_xor(m, s));
    if ((tid & 63) == 0) redm[tid >> 6] = m;
    __syncthreads();
    m = fmaxf(fmaxf(redm[0], redm[1]), fmaxf(redm[2], redm[3]));

    float sum = 0.f;
    #pragma unroll
    for (int i = 0; i < 8; ++i) {
        int t = tid + i * 256;
        v[i] = (t < len) ? __expf(v[i] - m) : 0.f;
        sum += v[i];
    }
    __shared__ float reds[4];
    #pragma unroll
    for (int s = 32; s; s >>= 1) sum += __shfl_xor(sum, s);
    if ((tid & 63) == 0) reds[tid >> 6] = sum;
    __syncthreads();
    sum = reds[0] + reds[1] + reds[2] + reds[3];
    float inv = 1.f / sum;
    #pragma unroll
    for (int i = 0; i < 8; ++i) {
        int t = tid + i * 256;
        row[t] = v[i] * inv;
    }
}

// ---- K3: context[b,e] = sum_t attn[b,t]*enc[b,t,e] ----
__global__ __launch_bounds__(256) void k_context(const float* __restrict__ enc,
                                                 const float* __restrict__ attn,
                                                 float* __restrict__ ctx) {
    int b = blockIdx.y, e0 = blockIdx.x * 128;
    int tid = threadIdx.x;
    int rg = tid >> 5, f4 = tid & 31;
    const float* encb = enc + (size_t)b * Tdim * Edim + e0 + f4 * 4;
    const float* arow = attn + (size_t)b * Tdim;
    float4 acc = make_float4(0.f, 0.f, 0.f, 0.f);
    for (int t = rg; t < Tdim; t += 8) {
        float a = arow[t];
        float4 v = *reinterpret_cast<const float4*>(encb + (size_t)t * Edim);
        acc.x += a * v.x; acc.y += a * v.y; acc.z += a * v.z; acc.w += a * v.w;
    }
    __shared__ float4 red[256];
    red[tid] = acc;
    __syncthreads();
    if (tid < 32) {
        float4 s = red[tid];
        #pragma unroll
        for (int g = 1; g < 8; ++g) {
            float4 o = red[g * 32 + tid];
            s.x += o.x; s.y += o.y; s.z += o.z; s.w += o.w;
        }
        *reinterpret_cast<float4*>(ctx + (size_t)b * Edim + e0 + tid * 4) = s;
    }
}

extern "C" void kernel_launch(void* const* d_in, const int* in_sizes, int n_in,
                              void* d_out, int out_size, void* d_ws, size_t ws_size,
                              hipStream_t stream) {
    const float* queries = (const float*)d_in[0];
    const float* prev    = (const float*)d_in[1];
    const float* enc     = (const float*)d_in[2];
    const float* conv_w  = (const float*)d_in[3];
    const float* conv_b  = (const float*)d_in[4];
    const float* Wq      = (const float*)d_in[5];
    const float* Wk      = (const float*)d_in[6];
    const float* v_w     = (const float*)d_in[7];
    const float* v_b     = (const float*)d_in[8];
    const float* bparam  = (const float*)d_in[9];
    const int*   lengths = (const int*)d_in[10];

    float* out  = (float*)d_out;
    float* ctx  = out;                       // B*E = 32768
    float* attn = out + Bsz * Edim;          // B*T = 131072 (scores staged here, then softmaxed in place)

    unsigned short* wkbf = (unsigned short*)d_ws;                       // 128 KB
    float* qb = (float*)((char*)d_ws + (size_t)Udim * Edim * 2);        // 32 KB

    k_cast_wk<<<64, 256, 0, stream>>>(Wk, wkbf);
    k_prep_qb<<<2048, 256, 0, stream>>>(queries, Wq, bparam, conv_b, qb);
    k_score<<<dim3(Tdim / 64, Bsz), 256, 0, stream>>>(enc, prev, wkbf, qb, conv_w, v_w, v_b, attn);
    k_softmax<<<Bsz, 256, 0, stream>>>(attn, lengths);
    k_context<<<dim3(Edim / 128, Bsz), 256, 0, stream>>>(enc, attn, ctx);
}

// Round 2
// 114.346 us; speedup vs baseline: 1.6041x; 1.6041x over previous
//
#include <hip/hip_runtime.h>
#include <hip/hip_bf16.h>

typedef __bf16 bf16x8 __attribute__((ext_vector_type(8)));
typedef float  f32x4  __attribute__((ext_vector_type(4)));

#define Bsz 64
#define Tdim 2048
#define Edim 512
#define Ddim 1024
#define Udim 128
#define NCHUNK 32          // Tdim / 64

__device__ inline unsigned short f2bf(float f) {
    union { float f; unsigned int u; } x{f};
    unsigned int r = x.u + 0x7FFFu + ((x.u >> 16) & 1u);   // RNE
    return (unsigned short)(r >> 16);
}

// ---- K0a: Wk (U,E) fp32 -> bf16 into ws ----
__global__ __launch_bounds__(256) void k_cast_wk(const float* __restrict__ Wk,
                                                 unsigned short* __restrict__ out) {
    int i = (blockIdx.x * 256 + threadIdx.x) * 4;
    float4 v = *reinterpret_cast<const float4*>(Wk + i);
    ushort4 h = make_ushort4(f2bf(v.x), f2bf(v.y), f2bf(v.z), f2bf(v.w));
    *reinterpret_cast<ushort4*>(out + i) = h;
}

// ---- K0b: qb[b,u] = queries[b]·Wq[u] + b[u] + conv_b[u] ----
__global__ __launch_bounds__(256) void k_prep_qb(const float* __restrict__ q,
                                                 const float* __restrict__ Wq,
                                                 const float* __restrict__ bparam,
                                                 const float* __restrict__ convb,
                                                 float* __restrict__ qb) {
    int gw   = blockIdx.x * 4 + (threadIdx.x >> 6);
    int lane = threadIdx.x & 63;
    int b = gw >> 7, u = gw & 127;
    const float* qr = q  + (size_t)b * Ddim;
    const float* wr = Wq + (size_t)u * Ddim;
    float s = 0.f;
    #pragma unroll
    for (int i = 0; i < 4; ++i) {
        int base = lane * 16 + i * 4;
        float4 a = *reinterpret_cast<const float4*>(qr + base);
        float4 w = *reinterpret_cast<const float4*>(wr + base);
        s += a.x * w.x + a.y * w.y + a.z * w.z + a.w * w.w;
    }
    #pragma unroll
    for (int m = 32; m; m >>= 1) s += __shfl_xor(s, m);
    if (lane == 0) qb[gw] = s + bparam[u] + convb[u];
}

// ---- K1: fused score + partial softmax + partial context ----
// block: 256 thr (4 waves); tile 64 t x 128 u; per-chunk partials (m,l,c[512]) to ws
__global__ __launch_bounds__(256) void k_score_ctx(const float* __restrict__ enc,
                                                   const float* __restrict__ prev,
                                                   const unsigned short* __restrict__ wkbf,
                                                   const float* __restrict__ qb,
                                                   const float* __restrict__ conv_w,
                                                   const float* __restrict__ v_w,
                                                   const float* __restrict__ v_b,
                                                   const int* __restrict__ lengths,
                                                   float* __restrict__ score_out,
                                                   float* __restrict__ m_ws,
                                                   float* __restrict__ l_ws,
                                                   float* __restrict__ c_ws) {
    __shared__ alignas(16) unsigned short At[64 * 64];      // 8 KB, swizzled
    __shared__ alignas(16) unsigned short Bt[128 * 64];     // 16 KB, swizzled
    __shared__ float s_prev[66];
    __shared__ float s_qb[128];
    __shared__ float s_vw[128];
    __shared__ float s_cw[3][128];
    __shared__ float s_score[64];
    __shared__ float s_p[64];
    __shared__ alignas(16) float s_cred[128 * 4];           // 2 KB reduce buffer

    const int tid   = threadIdx.x;
    const int b     = blockIdx.y;
    const int chunk = blockIdx.x;
    const int t0    = chunk * 64;
    const int lane  = tid & 63, wid = tid >> 6;
    const int len   = lengths[b];
    const int pidx  = b * NCHUNK + chunk;

    // fully-masked chunk: write empty partial, exit (saves the whole tile's HBM read)
    if (t0 >= len) {
        if (tid == 0) { m_ws[pidx] = -3.4e38f; l_ws[pidx] = 0.f; }
        return;
    }

    if (tid < 128) {
        s_qb[tid]    = qb[b * 128 + tid];
        s_vw[tid]    = v_w[tid];
        s_cw[0][tid] = conv_w[tid * 3 + 0];
        s_cw[1][tid] = conv_w[tid * 3 + 1];
        s_cw[2][tid] = conv_w[tid * 3 + 2];
    }
    if (tid < 66) {
        int idx = t0 - 1 + tid;
        s_prev[tid] = (idx >= 0 && idx < Tdim) ? prev[b * Tdim + idx] : 0.f;
    }

    f32x4 acc[8];
    #pragma unroll
    for (int n = 0; n < 8; ++n) acc[n] = (f32x4){0.f, 0.f, 0.f, 0.f};

    const float* encb = enc + ((size_t)b * Tdim + t0) * Edim;

    for (int e0 = 0; e0 < Edim; e0 += 64) {
        #pragma unroll
        for (int i = 0; i < 4; ++i) {
            int lin = tid + i * 256;
            int r = lin >> 4, c4 = lin & 15;
            float4 v = *reinterpret_cast<const float4*>(encb + (size_t)r * Edim + e0 + c4 * 4);
            ushort4 h = make_ushort4(f2bf(v.x), f2bf(v.y), f2bf(v.z), f2bf(v.w));
            int off = (r * 128 + c4 * 8) ^ ((r & 7) << 4);
            *reinterpret_cast<ushort4*>(reinterpret_cast<char*>(At) + off) = h;
        }
        #pragma unroll
        for (int i = 0; i < 4; ++i) {
            int lin = tid + i * 256;
            int u = lin >> 3, c8 = lin & 7;
            uint4 w = *reinterpret_cast<const uint4*>(wkbf + (size_t)u * Edim + e0 + c8 * 8);
            int off = (u * 128 + c8 * 16) ^ ((u & 7) << 4);
            *reinterpret_cast<uint4*>(reinterpret_cast<char*>(Bt) + off) = w;
        }
        __syncthreads();
        #pragma unroll
        for (int kk = 0; kk < 2; ++kk) {
            int ar = wid * 16 + (lane & 15);
            int abyte = (ar * 128 + kk * 64 + (lane >> 4) * 16) ^ ((ar & 7) << 4);
            bf16x8 af = *reinterpret_cast<const bf16x8*>(reinterpret_cast<char*>(At) + abyte);
            #pragma unroll
            for (int n = 0; n < 8; ++n) {
                int br = n * 16 + (lane & 15);
                int bbyte = (br * 128 + kk * 64 + (lane >> 4) * 16) ^ ((br & 7) << 4);
                bf16x8 bv = *reinterpret_cast<const bf16x8*>(reinterpret_cast<char*>(Bt) + bbyte);
                acc[n] = __builtin_amdgcn_mfma_f32_16x16x32_bf16(af, bv, acc[n], 0, 0, 0);
            }
        }
        __syncthreads();
    }

    // epilogue: score = v·tanh(acc + qb + conv) + v_b
    float sc[4] = {0.f, 0.f, 0.f, 0.f};
    #pragma unroll
    for (int n = 0; n < 8; ++n) {
        int u = n * 16 + (lane & 15);
        float c0 = s_cw[0][u], c1 = s_cw[1][u], c2 = s_cw[2][u];
        float qbu = s_qb[u], vwu = s_vw[u];
        #pragma unroll
        for (int j = 0; j < 4; ++j) {
            int tl = wid * 16 + (lane >> 4) * 4 + j;
            float conv = s_prev[tl] * c0 + s_prev[tl + 1] * c1 + s_prev[tl + 2] * c2;
            sc[j] += vwu * tanhf(acc[n][j] + qbu + conv);
        }
    }
    #pragma unroll
    for (int j = 0; j < 4; ++j) {
        sc[j] += __shfl_xor(sc[j], 1);
        sc[j] += __shfl_xor(sc[j], 2);
        sc[j] += __shfl_xor(sc[j], 4);
        sc[j] += __shfl_xor(sc[j], 8);
    }
    if ((lane & 15) == 0) {
        float vb = v_b[0];
        int tl = wid * 16 + (lane >> 4) * 4;
        #pragma unroll
        for (int j = 0; j < 4; ++j) {
            float s = sc[j] + vb;
            s_score[tl + j] = s;
            score_out[b * Tdim + t0 + tl + j] = s;   // raw score; normalized by k_combine
        }
    }
    __syncthreads();

    // partial softmax over this chunk's 64 rows (each wave redundantly, lane t = lane)
    float sv = (t0 + lane < len) ? s_score[lane] : -3.4e38f;
    float m = sv;
    #pragma unroll
    for (int s = 32; s; s >>= 1) m = fmaxf(m, __shfl_xor(m, s));
    float p = (t0 + lane < len) ? __expf(sv - m) : 0.f;
    float l = p;
    #pragma unroll
    for (int s = 32; s; s >>= 1) l += __shfl_xor(l, s);
    if (tid < 64) s_p[tid] = p;
    if (tid == 0) { m_ws[pidx] = m; l_ws[pidx] = l; }
    __syncthreads();

    // partial context: c[e] = sum_t p_t * enc[t,e]  (enc tile re-read; L2/L3-hot)
    {
        int e4 = (tid & 127) * 4;
        int th = tid >> 7;
        float4 a = make_float4(0.f, 0.f, 0.f, 0.f);
        for (int t = th; t < 64; t += 2) {
            float pt = s_p[t];
            float4 v = *reinterpret_cast<const float4*>(encb + (size_t)t * Edim + e4);
            a.x += pt * v.x; a.y += pt * v.y; a.z += pt * v.z; a.w += pt * v.w;
        }
        if (th == 1) *reinterpret_cast<float4*>(&s_cred[(tid & 127) * 4]) = a;
        __syncthreads();
        if (th == 0) {
            float4 o = *reinterpret_cast<const float4*>(&s_cred[tid * 4]);
            a.x += o.x; a.y += o.y; a.z += o.z; a.w += o.w;
            *reinterpret_cast<float4*>(c_ws + (size_t)pidx * Edim + e4) = a;
        }
    }
}

// ---- K2: combine partials -> context + normalized attn ----
__global__ __launch_bounds__(256) void k_combine(const float* __restrict__ m_ws,
                                                 const float* __restrict__ l_ws,
                                                 const float* __restrict__ c_ws,
                                                 const int* __restrict__ lengths,
                                                 float* __restrict__ ctx,
                                                 float* __restrict__ attn) {
    int b = blockIdx.x, tid = threadIdx.x;
    int lane = tid & 63, wid = tid >> 6;
    __shared__ float s_w[NCHUNK];
    __shared__ float sM, sinvL;

    if (wid == 0) {
        float mj = (lane < NCHUNK) ? m_ws[b * NCHUNK + lane] : -3.4e38f;
        float lj = (lane < NCHUNK) ? l_ws[b * NCHUNK + lane] : 0.f;
        float M = mj;
        #pragma unroll
        for (int s = 32; s; s >>= 1) M = fmaxf(M, __shfl_xor(M, s));
        float w = (lj > 0.f) ? __expf(mj - M) : 0.f;
        float L = lj * w;
        #pragma unroll
        for (int s = 32; s; s >>= 1) L += __shfl_xor(L, s);
        if (lane < NCHUNK) s_w[lane] = w;
        if (lane == 0) { sM = M; sinvL = 1.f / L; }
    }
    __syncthreads();
    float M = sM, invL = sinvL;

    // context: each thread owns 2 consecutive e columns
    {
        int e2 = tid * 2;
        float ax = 0.f, ay = 0.f;
        #pragma unroll 4
        for (int j = 0; j < NCHUNK; ++j) {
            float w = s_w[j];
            if (w != 0.f) {
                float2 v = *reinterpret_cast<const float2*>(c_ws + ((size_t)(b * NCHUNK + j)) * Edim + e2);
                ax += w * v.x; ay += w * v.y;
            }
        }
        float2 r = make_float2(ax * invL, ay * invL);
        *reinterpret_cast<float2*>(ctx + (size_t)b * Edim + e2) = r;
    }

    // attn: normalize raw scores in place
    int len = lengths[b];
    #pragma unroll
    for (int i = 0; i < Tdim / 256; ++i) {
        int t = tid + i * 256;
        float s = attn[(size_t)b * Tdim + t];
        attn[(size_t)b * Tdim + t] = (t < len) ? __expf(s - M) * invL : 0.f;
    }
}

extern "C" void kernel_launch(void* const* d_in, const int* in_sizes, int n_in,
                              void* d_out, int out_size, void* d_ws, size_t ws_size,
                              hipStream_t stream) {
    const float* queries = (const float*)d_in[0];
    const float* prev    = (const float*)d_in[1];
    const float* enc     = (const float*)d_in[2];
    const float* conv_w  = (const float*)d_in[3];
    const float* conv_b  = (const float*)d_in[4];
    const float* Wq      = (const float*)d_in[5];
    const float* Wk      = (const float*)d_in[6];
    const float* v_w     = (const float*)d_in[7];
    const float* v_b     = (const float*)d_in[8];
    const float* bparam  = (const float*)d_in[9];
    const int*   lengths = (const int*)d_in[10];

    float* out  = (float*)d_out;
    float* ctx  = out;                       // B*E = 32768
    float* attn = out + Bsz * Edim;          // B*T = 131072 (raw scores -> normalized in place)

    char* ws = (char*)d_ws;
    unsigned short* wkbf = (unsigned short*)ws;                 ws += (size_t)Udim * Edim * 2;  // 128 KB
    float* qb   = (float*)ws;                                   ws += (size_t)Bsz * Udim * 4;   // 32 KB
    float* m_ws = (float*)ws;                                   ws += (size_t)Bsz * NCHUNK * 4; // 8 KB
    float* l_ws = (float*)ws;                                   ws += (size_t)Bsz * NCHUNK * 4; // 8 KB
    float* c_ws = (float*)ws;                                   // B*NCHUNK*E*4 = 4 MB

    k_cast_wk<<<64, 256, 0, stream>>>(Wk, wkbf);
    k_prep_qb<<<2048, 256, 0, stream>>>(queries, Wq, bparam, conv_b, qb);
    k_score_ctx<<<dim3(NCHUNK, Bsz), 256, 0, stream>>>(enc, prev, wkbf, qb, conv_w, v_w, v_b,
                                                       lengths, attn, m_ws, l_ws, c_ws);
    k_combine<<<Bsz, 256, 0, stream>>>(m_ws, l_ws, c_ws, lengths, ctx, attn);
}